// Round 9
// baseline (311.228 us; speedup 1.0000x reference)
//
#include <hip/hip_runtime.h>

// LSTM B=8192, T=512, I=1, H=32; out[b] = h_T . W_lin + b_lin.  All I/O f32.
//
// MFMA formulation, R7 split + DUAL-GROUP interleave.
// Block = 256 threads = 4 waves, processes TWO 16-batch groups (A = base,
// B = base+16). Grid = 256 blocks = 1024 waves = exactly 1 wave/SIMD.
// Wave wv: half = wv>>1 (hidden half), rsel = wv&1 (r-pair). Wave computes
// tiles {half,2+half,4+half,6+half} for BOTH groups (A-fragments shared),
// activating r-pair {2rsel,2rsel+1} via the col^2 A-row permutation trick
// (row-permuting A permutes D rows identically -> owned gates in slots 0,1).
//   lane(quad,col) owns hiddens j0=16half+4quad+2rsel, j0+1 of batch col.
//
// R8 post-mortem: 8-way split regressed (MFMA dup x4 = 276 cyc/SIMD issue,
// LDS conflicts doubled). R7's residue is ~364 cyc/step exposed latency
// (barrier->ds_read->MFMA->trans chains). Fix: a second INDEPENDENT chain
// per wave (group B) fills group A's latency; one barrier serves both.
// x stored in LDS as f16 [b][t], b-stride 520 halves (fits 2 groups in
// static LDS; read aliasing 2-way = free).
// Pre-acts pre-scaled by log2e (2*log2e for tanh gate):
//   sigmoid(z)=rcp(1+exp2(-acc)), tanh(z)=2*rcp(1+exp2(-2*L2E*z'))-1.

#define L2E 1.4426950408889634f

typedef _Float16 f16x8 __attribute__((ext_vector_type(8)));
typedef _Float16 f16x4 __attribute__((ext_vector_type(4)));
typedef float    f32x4 __attribute__((ext_vector_type(4)));

__global__ __launch_bounds__(256, 1) void lstm_dual(
    const float* __restrict__ x,      // [B*512]
    const float* __restrict__ W_ih,   // [128]
    const float* __restrict__ W_hh,   // [128*32]
    const float* __restrict__ b_ih,   // [128]
    const float* __restrict__ b_hh,   // [128]
    const float* __restrict__ W_lin,  // [32]
    const float* __restrict__ b_lin,  // [1]
    float* __restrict__ out)          // [B]
{
    __shared__ __align__(16) _Float16 xs[2][16 * 520];        // [grp][b][t], b-stride 520 halves
    __shared__ __align__(16) unsigned int hb[2][2][16 * 20];  // [grp][buf][pairs], col-stride 20
    __shared__ float ps[2][64];                               // epilogue partials

    const int tid  = threadIdx.x;
    const int wv   = tid >> 6;         // 0..3
    const int half = wv >> 1;          // hidden half 0/1
    const int rsel = wv & 1;           // r-pair select
    const int lane = tid & 63;
    const int col  = lane & 15;        // batch within group
    const int quad = lane >> 4;        // 0..3
    const int base = blockIdx.x * 32;  // global batch base (2 groups)

    // ---- stage x[base..base+31][0..511] into LDS as f16 [grp][b][t] ----
    {
        const float4* xg = (const float4*)(x + (size_t)base * 512);
        #pragma unroll
        for (int it = 0; it < 16; ++it) {
            int idx = it * 256 + tid;          // 0..4095 float4s
            float4 v = xg[idx];
            int b  = idx >> 7;                 // batch 0..31
            int t0 = (idx & 127) * 4;
            f16x4 hv;
            hv[0] = (_Float16)v.x; hv[1] = (_Float16)v.y;
            hv[2] = (_Float16)v.z; hv[3] = (_Float16)v.w;
            *(f16x4*)&xs[b >> 4][(b & 15) * 520 + t0] = hv;   // ds_write_b64
        }
    }

    // ---- per-wave weights: tiles 2T+half, A-rows permuted by ^(rsel<<1) ----
    f16x8 wA[4];
    float wih2[4][2], bia2[4][2];
    #pragma unroll
    for (int T = 0; T < 4; ++T) {
        const int tile = 2 * T + half;
        const float s = (T == 2) ? (2.0f * L2E) : L2E;
        const int ga = 16 * tile + (col ^ (rsel << 1));   // permuted A row
        #pragma unroll
        for (int j = 0; j < 8; ++j)
            wA[T][j] = (_Float16)(W_hh[ga * 32 + quad * 8 + j] * s);
        #pragma unroll
        for (int r = 0; r < 2; ++r) {
            const int g = 16 * tile + quad * 4 + 2 * rsel + r;  // owned D row's gate
            wih2[T][r] = W_ih[g] * s;
            bia2[T][r] = (b_ih[g] + b_hh[g]) * s;
        }
    }
    const int j0 = 16 * half + 4 * quad + 2 * rsel;  // first owned hidden
    const float wl0 = W_lin[j0], wl1 = W_lin[j0 + 1];
    const int pr = 8 * half + 2 * quad + rsel;       // h-pair index = j0/2

    __syncthreads();

    float cA0 = 0.f, cA1 = 0.f, hA0 = 0.f, hA1 = 0.f;
    float cB0 = 0.f, cB1 = 0.f, hB0 = 0.f, hB1 = 0.f;
    f16x8 bfA = {}, bfB = {};
    f32x4 cqA[4] = {{0,0,0,0},{0,0,0,0},{0,0,0,0},{0,0,0,0}};
    f32x4 cqB[4] = {{0,0,0,0},{0,0,0,0},{0,0,0,0},{0,0,0,0}};
    {
        float xA = (float)xs[0][col * 520];     // t = 0
        float xB = (float)xs[1][col * 520];
        #pragma unroll
        for (int T = 0; T < 4; ++T) {
            cqA[T][0] = fmaf(xA, wih2[T][0], bia2[T][0]);
            cqA[T][1] = fmaf(xA, wih2[T][1], bia2[T][1]);
            cqB[T][0] = fmaf(xB, wih2[T][0], bia2[T][0]);
            cqB[T][1] = fmaf(xB, wih2[T][1], bia2[T][1]);
        }
    }

    // activation for one group's 2 owned hiddens (slots 0,1 of acc)
    auto act = [&](const f32x4* acc, float& c0, float& c1, float& h0, float& h1) {
        float ei0 = __builtin_amdgcn_exp2f(-acc[0][0]);
        float ef0 = __builtin_amdgcn_exp2f(-acc[1][0]);
        float eg0 = __builtin_amdgcn_exp2f(-acc[2][0]);
        float eo0 = __builtin_amdgcn_exp2f(-acc[3][0]);
        float ei1 = __builtin_amdgcn_exp2f(-acc[0][1]);
        float ef1 = __builtin_amdgcn_exp2f(-acc[1][1]);
        float eg1 = __builtin_amdgcn_exp2f(-acc[2][1]);
        float eo1 = __builtin_amdgcn_exp2f(-acc[3][1]);
        float si0 = __builtin_amdgcn_rcpf(1.0f + ei0);
        float sf0 = __builtin_amdgcn_rcpf(1.0f + ef0);
        float sg0 = __builtin_amdgcn_rcpf(1.0f + eg0);
        float so0 = __builtin_amdgcn_rcpf(1.0f + eo0);
        float si1 = __builtin_amdgcn_rcpf(1.0f + ei1);
        float sf1 = __builtin_amdgcn_rcpf(1.0f + ef1);
        float sg1 = __builtin_amdgcn_rcpf(1.0f + eg1);
        float so1 = __builtin_amdgcn_rcpf(1.0f + eo1);
        float gg0 = fmaf(2.0f, sg0, -1.0f);
        float gg1 = fmaf(2.0f, sg1, -1.0f);
        c0 = fmaf(sf0, c0, si0 * gg0);
        c1 = fmaf(sf1, c1, si1 * gg1);
        float tc0 = __builtin_amdgcn_rcpf(1.0f + __builtin_amdgcn_exp2f(c0 * (-2.0f * L2E)));
        float tc1 = __builtin_amdgcn_rcpf(1.0f + __builtin_amdgcn_exp2f(c1 * (-2.0f * L2E)));
        h0 = so0 * fmaf(2.0f, tc0, -1.0f);
        h1 = so1 * fmaf(2.0f, tc1, -1.0f);
    };

    #pragma unroll 2
    for (int t = 0; t < 512; ++t) {
        unsigned int* bufA = hb[0][t & 1];
        unsigned int* bufB = hb[1][t & 1];

        f32x4 aA[4], aB[4];
        #pragma unroll
        for (int T = 0; T < 4; ++T)
            aA[T] = __builtin_amdgcn_mfma_f32_16x16x32_f16(wA[T], bfA, cqA[T], 0, 0, 0);
        #pragma unroll
        for (int T = 0; T < 4; ++T)
            aB[T] = __builtin_amdgcn_mfma_f32_16x16x32_f16(wA[T], bfB, cqB[T], 0, 0, 0);

        // prefetch next x for both groups (independent of h)
        float xA1 = (float)xs[0][col * 520 + ((t + 1) & 511)];
        float xB1 = (float)xs[1][col * 520 + ((t + 1) & 511)];

        // two independent activation chains — compiler interleaves them
        act(aA, cA0, cA1, hA0, hA1);
        bufA[col * 20 + pr] =
            __builtin_bit_cast(unsigned int, __builtin_amdgcn_cvt_pkrtz(hA0, hA1));
        act(aB, cB0, cB1, hB0, hB1);
        bufB[col * 20 + pr] =
            __builtin_bit_cast(unsigned int, __builtin_amdgcn_cvt_pkrtz(hB0, hB1));

        // next step's C-init in the pre-barrier slack
        #pragma unroll
        for (int T = 0; T < 4; ++T) {
            cqA[T][0] = fmaf(xA1, wih2[T][0], bia2[T][0]);
            cqA[T][1] = fmaf(xA1, wih2[T][1], bia2[T][1]);
            cqB[T][0] = fmaf(xB1, wih2[T][0], bia2[T][0]);
            cqB[T][1] = fmaf(xB1, wih2[T][1], bia2[T][1]);
        }

        __syncthreads();
        // B-frags: pairs quad*4..+3 of batch col = k quad*8..quad*8+7
        bfA = __builtin_bit_cast(f16x8, *(const uint4*)&bufA[col * 20 + quad * 4]);
        bfB = __builtin_bit_cast(f16x8, *(const uint4*)&bufB[col * 20 + quad * 4]);
    }

    // ---- epilogue: out[b] = sum_j h_j * W_lin[j] + b_lin ----
    float vA = fmaf(hA0, wl0, hA1 * wl1);
    float vB = fmaf(hB0, wl0, hB1 * wl1);
    vA += __shfl_xor(vA, 16);  vA += __shfl_xor(vA, 32);
    vB += __shfl_xor(vB, 16);  vB += __shfl_xor(vB, 32);
    if (lane < 16) {
        ps[0][wv * 16 + col] = vA;
        ps[1][wv * 16 + col] = vB;
    }
    __syncthreads();
    if (tid < 32) {
        int grp = tid >> 4, b = tid & 15;
        out[base + grp * 16 + b] = b_lin[0] + ps[grp][b] + ps[grp][16 + b]
                                 + ps[grp][32 + b] + ps[grp][48 + b];
    }
}

extern "C" void kernel_launch(void* const* d_in, const int* in_sizes, int n_in,
                              void* d_out, int out_size, void* d_ws, size_t ws_size,
                              hipStream_t stream) {
    const float* x     = (const float*)d_in[0];
    const float* W_ih  = (const float*)d_in[1];
    const float* W_hh  = (const float*)d_in[2];
    const float* b_ih  = (const float*)d_in[3];
    const float* b_hh  = (const float*)d_in[4];
    const float* W_lin = (const float*)d_in[5];
    const float* b_lin = (const float*)d_in[6];
    float* out = (float*)d_out;

    const int B = in_sizes[0] / 512;   // 8192
    dim3 grid(B / 32), block(256);
    lstm_dual<<<grid, block, 0, stream>>>(x, W_ih, W_hh, b_ih, b_hh, W_lin, b_lin, out);
}

// Round 10
// 237.638 us; speedup vs baseline: 1.3097x; 1.3097x over previous
//
#include <hip/hip_runtime.h>

// LSTM B=8192, T=512, I=1, H=32; out[b] = h_T . W_lin + b_lin.  All I/O f32.
//
// MFMA formulation, 8 waves per 16-batch group (512 blocks x 512 threads),
// NO MFMA duplication via CUSTOM TILES, fused-rcp activations.
//
// Wave wv: hf = wv>>2 (hidden half), rs = wv&3. Lane (quad,col) owns hidden
// j = 16hf + 4quad + rs of batch col. Custom A-tile per wave: row m holds
// gate-row [type m&3, hidden 16hf+4(m>>2)+rs] of W_hh (row permutation of A
// permutes D rows identically), so ONE mfma_f32_16x16x32_f16 delivers the
// lane's {i,f,g,o} pre-acts in acc slots 0..3. 8 waves x 1 tile = 128 gates,
// zero duplication (R8's 4x-dup tax removed). 4096 waves = 4/SIMD.
//
// Fused-rcp activations (10 -> 7 trans/hidden): with e* = 2^(-z*'),
//   a* = 1+e*;  c' = (c*aI*aG + (1-eG)*aF) * rcp(aF*aI*aG)
//   eC = 2^(-2*L2E*c'); h = (1-eC) * rcp(aO*(1+eC))
// Pre-acts pre-scaled by L2E (2*L2E for the g/tanh gate).
//
// R9 post-mortem: 1 wave/SIMD structures (R5/R9) lose to 2/SIMD (R7) because
// a wave's barrier stall blocks everything; R8's 4/SIMD lost to MFMA-dup tax.
// This keeps 4/SIMD chains with per-SIMD busy ~592 cyc/step (< R7's 644).

#define L2E 1.4426950408889634f

typedef _Float16 f16x8 __attribute__((ext_vector_type(8)));
typedef float    f32x4 __attribute__((ext_vector_type(4)));

__global__ __launch_bounds__(512, 4) void lstm_ctile(
    const float* __restrict__ x,      // [B*512]
    const float* __restrict__ W_ih,   // [128]
    const float* __restrict__ W_hh,   // [128*32]
    const float* __restrict__ b_ih,   // [128]
    const float* __restrict__ b_hh,   // [128]
    const float* __restrict__ W_lin,  // [32]
    const float* __restrict__ b_lin,  // [1]
    float* __restrict__ out)          // [B]
{
    __shared__ float xs[512 * 17];                        // x transposed [t][b], stride 17
    __shared__ __align__(16) unsigned int hb[2][16 * 20]; // h f16 buffers, col-stride 20 uints
    __shared__ float ps[128];                             // epilogue partials

    const int tid  = threadIdx.x;
    const int wv   = tid >> 6;         // 0..7
    const int hf   = wv >> 2;          // hidden half 0/1
    const int rs   = wv & 3;           // row-within-quad select
    const int lane = tid & 63;
    const int col  = lane & 15;        // batch within group
    const int quad = lane >> 4;        // 0..3
    const int base = blockIdx.x * 16;  // global batch base

    // ---- stage x[base..base+15][0..511] into LDS transposed ----
    {
        const float4* xg = (const float4*)(x + (size_t)base * 512);
        #pragma unroll
        for (int it = 0; it < 4; ++it) {
            int idx = it * 512 + tid;          // 0..2047 float4s
            float4 v = xg[idx];
            int b  = idx >> 7;                 // batch 0..15
            int t0 = (idx & 127) * 4;
            xs[(t0 + 0) * 17 + b] = v.x;
            xs[(t0 + 1) * 17 + b] = v.y;
            xs[(t0 + 2) * 17 + b] = v.z;
            xs[(t0 + 3) * 17 + b] = v.w;
        }
    }

    // ---- custom A-tile: row m = gate[type m&3][hidden 16hf+4(m>>2)+rs] ----
    // lane (quad,col) holds A[m=col][k=8*quad..+7]
    f16x8 wA;
    {
        const int Tm = col & 3;                           // gate type of row col
        const float s = (Tm == 2) ? (2.0f * L2E) : L2E;
        const int grow = 32 * Tm + 16 * hf + 4 * (col >> 2) + rs;
        #pragma unroll
        for (int j = 0; j < 8; ++j)
            wA[j] = (_Float16)(W_hh[grow * 32 + quad * 8 + j] * s);
    }
    // C-init constants: acc slot r = gate type r of owned hidden j
    const int jj = 16 * hf + 4 * quad + rs;               // owned hidden 0..31
    float wih1[4], bia1[4];
    #pragma unroll
    for (int r = 0; r < 4; ++r) {
        const float s = (r == 2) ? (2.0f * L2E) : L2E;
        const int g = 32 * r + jj;
        wih1[r] = W_ih[g] * s;
        bia1[r] = (b_ih[g] + b_hh[g]) * s;
    }
    const float wl = W_lin[jj];

    __syncthreads();

    float c0 = 0.0f, h0 = 0.0f;
    f16x8 bfrag = {};                  // h = 0
    f32x4 cq;
    {
        float xt = xs[col];            // t = 0
        #pragma unroll
        for (int r = 0; r < 4; ++r)
            cq[r] = fmaf(xt, wih1[r], bia1[r]);
    }

    #pragma unroll 2
    for (int t = 0; t < 512; ++t) {
        unsigned int* buf = hb[t & 1];

        f32x4 acc = __builtin_amdgcn_mfma_f32_16x16x32_f16(wA, bfrag, cq, 0, 0, 0);

        float xt1 = xs[((t + 1) & 511) * 17 + col];       // prefetch next x

        // fused-rcp activations: slots 0=i,1=f,2=g,3=o
        float ei = __builtin_amdgcn_exp2f(-acc[0]);
        float ef = __builtin_amdgcn_exp2f(-acc[1]);
        float eg = __builtin_amdgcn_exp2f(-acc[2]);
        float eo = __builtin_amdgcn_exp2f(-acc[3]);
        float aI = 1.0f + ei, aF = 1.0f + ef, aG = 1.0f + eg, aO = 1.0f + eo;
        float gN = 1.0f - eg;
        float tIG = aI * aG;
        float num = fmaf(c0, tIG, gN * aF);
        float rcD = __builtin_amdgcn_rcpf(aF * tIG);
        c0 = num * rcD;                                    // c_t
        float ec = __builtin_amdgcn_exp2f(c0 * (-2.0f * L2E));
        float aC = 1.0f + ec, cN = 1.0f - ec;
        float rcH = __builtin_amdgcn_rcpf(aO * aC);
        h0 = cN * rcH;                                     // o * tanh(c)

        // write this lane's h as one f16 halfword: short index col*40 + jj
        ((short*)buf)[col * 40 + jj] =
            (short)__builtin_bit_cast(unsigned short, (_Float16)h0);

        // next step's C-init in the pre-barrier slack
        #pragma unroll
        for (int r = 0; r < 4; ++r)
            cq[r] = fmaf(xt1, wih1[r], bia1[r]);

        __syncthreads();
        // B-frag: shorts col*40 + 8*quad..+7 = uints col*20 + quad*4..+3
        uint4 bv = *(const uint4*)&buf[col * 20 + quad * 4];
        bfrag = __builtin_bit_cast(f16x8, bv);
    }

    // ---- epilogue: out[b] = sum_j h_j * W_lin[j] + b_lin ----
    float v = h0 * wl;
    v += __shfl_xor(v, 16);            // combine quads
    v += __shfl_xor(v, 32);
    if (lane < 16) ps[wv * 16 + col] = v;
    __syncthreads();
    if (tid < 16) {
        float s = b_lin[0];
        #pragma unroll
        for (int w = 0; w < 8; ++w) s += ps[w * 16 + tid];
        out[base + tid] = s;
    }
}

extern "C" void kernel_launch(void* const* d_in, const int* in_sizes, int n_in,
                              void* d_out, int out_size, void* d_ws, size_t ws_size,
                              hipStream_t stream) {
    const float* x     = (const float*)d_in[0];
    const float* W_ih  = (const float*)d_in[1];
    const float* W_hh  = (const float*)d_in[2];
    const float* b_ih  = (const float*)d_in[3];
    const float* b_hh  = (const float*)d_in[4];
    const float* W_lin = (const float*)d_in[5];
    const float* b_lin = (const float*)d_in[6];
    float* out = (float*)d_out;

    const int B = in_sizes[0] / 512;   // 8192
    dim3 grid(B / 16), block(512);
    lstm_ctile<<<grid, block, 0, stream>>>(x, W_ih, W_hh, b_ih, b_hh, W_lin, b_lin, out);
}

// Round 11
// 221.967 us; speedup vs baseline: 1.4021x; 1.0706x over previous
//
#include <hip/hip_runtime.h>

// LSTM B=8192, T=512, I=1, H=32; out[b] = h_T . W_lin + b_lin.  All I/O f32.
//
// MFMA formulation, 4 waves per 16-batch group (512 blocks x 256 threads),
// custom tiles (zero MFMA duplication), 2 hiddens/lane, fused-rcp acts.
//
// Wave wv owns hiddens [8wv, 8wv+8). Lane (quad,col) owns j0 = 8wv+2quad+0
// and j1 = j0+1 of batch col. Custom A-tile tau (tau=0,1): row m = 4q+r
// holds W_hh gate-row [type r][hidden 8wv+2q+tau] (row-permuting A permutes
// D rows identically), so acc[tau] slots 0..3 = {i,f,g,o} pre-acts of
// hidden j0+tau -> compile-time slots, 2 MFMAs/wave-step, no duplication.
// 2048 waves = 2/SIMD; vs R10: busy/SIMD ~420 (-120), LDS read burst and
// barrier width halved; exposure grows ~+75 (2 vs 4 chains) -> net win.
//
// Fused-rcp activations (7 trans/hidden): e* = 2^(-z*'), a* = 1+e*,
//   c' = (c*aI*aG + (1-eG)*aF) * rcp(aF*aI*aG)
//   eC = 2^(-2*L2E*c'); h = (1-eC) * rcp(aO*(1+eC))
// Pre-acts pre-scaled by L2E (2*L2E for the g gate).

#define L2E 1.4426950408889634f

typedef _Float16 f16x8 __attribute__((ext_vector_type(8)));
typedef float    f32x4 __attribute__((ext_vector_type(4)));

__global__ __launch_bounds__(256, 4) void lstm_ct4(
    const float* __restrict__ x,      // [B*512]
    const float* __restrict__ W_ih,   // [128]
    const float* __restrict__ W_hh,   // [128*32]
    const float* __restrict__ b_ih,   // [128]
    const float* __restrict__ b_hh,   // [128]
    const float* __restrict__ W_lin,  // [32]
    const float* __restrict__ b_lin,  // [1]
    float* __restrict__ out)          // [B]
{
    __shared__ float xs[512 * 17];                        // x transposed [t][b], stride 17
    __shared__ __align__(16) unsigned int hb[2][16 * 20]; // h half2 buffers, col-stride 20 uints
    __shared__ float ps[64];                              // epilogue partials

    const int tid  = threadIdx.x;
    const int wv   = tid >> 6;         // 0..3: owns hiddens [8wv, 8wv+8)
    const int lane = tid & 63;
    const int col  = lane & 15;        // batch within group
    const int quad = lane >> 4;        // 0..3
    const int base = blockIdx.x * 16;  // global batch base

    // ---- stage x[base..base+15][0..511] into LDS transposed ----
    {
        const float4* xg = (const float4*)(x + (size_t)base * 512);
        #pragma unroll
        for (int it = 0; it < 8; ++it) {
            int idx = it * 256 + tid;          // 0..2047 float4s
            float4 v = xg[idx];
            int b  = idx >> 7;                 // batch 0..15
            int t0 = (idx & 127) * 4;
            xs[(t0 + 0) * 17 + b] = v.x;
            xs[(t0 + 1) * 17 + b] = v.y;
            xs[(t0 + 2) * 17 + b] = v.z;
            xs[(t0 + 3) * 17 + b] = v.w;
        }
    }

    // ---- custom A-tiles: tile tau row m=4a+rt -> W_hh[32*rt + 8wv+2a+tau] ----
    // lane (quad,col) holds A[m=col][k=8*quad..+7]
    f16x8 wA[2];
    #pragma unroll
    for (int tau = 0; tau < 2; ++tau) {
        const int rt = col & 3;                           // gate type of row col
        const float s = (rt == 2) ? (2.0f * L2E) : L2E;
        const int grow = 32 * rt + 8 * wv + 2 * (col >> 2) + tau;
        #pragma unroll
        for (int j = 0; j < 8; ++j)
            wA[tau][j] = (_Float16)(W_hh[grow * 32 + quad * 8 + j] * s);
    }
    // C-init constants: acc[tau] slot r = gate type r of hidden j0+tau
    const int j0 = 8 * wv + 2 * quad;                     // first owned hidden
    float wih[2][4], bia[2][4];
    #pragma unroll
    for (int tau = 0; tau < 2; ++tau)
        #pragma unroll
        for (int r = 0; r < 4; ++r) {
            const float s = (r == 2) ? (2.0f * L2E) : L2E;
            const int g = 32 * r + j0 + tau;
            wih[tau][r] = W_ih[g] * s;
            bia[tau][r] = (b_ih[g] + b_hh[g]) * s;
        }
    const float wl0 = W_lin[j0], wl1 = W_lin[j0 + 1];

    __syncthreads();

    float c0 = 0.0f, c1 = 0.0f, h0 = 0.0f, h1 = 0.0f;
    f16x8 bfrag = {};                  // h = 0
    f32x4 cq[2];
    {
        float xt = xs[col];            // t = 0
        #pragma unroll
        for (int tau = 0; tau < 2; ++tau)
            #pragma unroll
            for (int r = 0; r < 4; ++r)
                cq[tau][r] = fmaf(xt, wih[tau][r], bia[tau][r]);
    }

    const int wr = col * 20 + 4 * wv + quad;   // h-pair write index (= j0/2 slot)

    #pragma unroll 4
    for (int t = 0; t < 512; ++t) {
        unsigned int* buf = hb[t & 1];

        f32x4 a0 = __builtin_amdgcn_mfma_f32_16x16x32_f16(wA[0], bfrag, cq[0], 0, 0, 0);
        f32x4 a1 = __builtin_amdgcn_mfma_f32_16x16x32_f16(wA[1], bfrag, cq[1], 0, 0, 0);

        float xt1 = xs[((t + 1) & 511) * 17 + col];       // prefetch next x

        // fused-rcp activations, hidden j0 (a0) and j0+1 (a1)
        float ei0 = __builtin_amdgcn_exp2f(-a0[0]);
        float ef0 = __builtin_amdgcn_exp2f(-a0[1]);
        float eg0 = __builtin_amdgcn_exp2f(-a0[2]);
        float eo0 = __builtin_amdgcn_exp2f(-a0[3]);
        float ei1 = __builtin_amdgcn_exp2f(-a1[0]);
        float ef1 = __builtin_amdgcn_exp2f(-a1[1]);
        float eg1 = __builtin_amdgcn_exp2f(-a1[2]);
        float eo1 = __builtin_amdgcn_exp2f(-a1[3]);
        float aI0 = 1.0f + ei0, aF0 = 1.0f + ef0, aG0 = 1.0f + eg0, aO0 = 1.0f + eo0;
        float aI1 = 1.0f + ei1, aF1 = 1.0f + ef1, aG1 = 1.0f + eg1, aO1 = 1.0f + eo1;
        float tIG0 = aI0 * aG0, tIG1 = aI1 * aG1;
        float num0 = fmaf(c0, tIG0, (1.0f - eg0) * aF0);
        float num1 = fmaf(c1, tIG1, (1.0f - eg1) * aF1);
        float rcD0 = __builtin_amdgcn_rcpf(aF0 * tIG0);
        float rcD1 = __builtin_amdgcn_rcpf(aF1 * tIG1);
        c0 = num0 * rcD0;
        c1 = num1 * rcD1;
        float ec0 = __builtin_amdgcn_exp2f(c0 * (-2.0f * L2E));
        float ec1 = __builtin_amdgcn_exp2f(c1 * (-2.0f * L2E));
        float rcH0 = __builtin_amdgcn_rcpf(aO0 * (1.0f + ec0));
        float rcH1 = __builtin_amdgcn_rcpf(aO1 * (1.0f + ec1));
        h0 = (1.0f - ec0) * rcH0;
        h1 = (1.0f - ec1) * rcH1;

        // adjacent hiddens -> one b32 write of the packed pair
        buf[wr] = __builtin_bit_cast(unsigned int, __builtin_amdgcn_cvt_pkrtz(h0, h1));

        // next step's C-init in the pre-barrier slack
        #pragma unroll
        for (int tau = 0; tau < 2; ++tau)
            #pragma unroll
            for (int r = 0; r < 4; ++r)
                cq[tau][r] = fmaf(xt1, wih[tau][r], bia[tau][r]);

        __syncthreads();
        // B-frag: pairs quad*4..+3 of batch col = k quad*8..quad*8+7
        uint4 bv = *(const uint4*)&buf[col * 20 + quad * 4];
        bfrag = __builtin_bit_cast(f16x8, bv);
    }

    // ---- epilogue: out[b] = sum_j h_j * W_lin[j] + b_lin ----
    float v = fmaf(h0, wl0, h1 * wl1);
    v += __shfl_xor(v, 16);            // combine quads
    v += __shfl_xor(v, 32);
    if (lane < 16) ps[wv * 16 + col] = v;
    __syncthreads();
    if (tid < 16)
        out[base + tid] = b_lin[0] + ps[tid] + ps[16 + tid] + ps[32 + tid] + ps[48 + tid];
}

extern "C" void kernel_launch(void* const* d_in, const int* in_sizes, int n_in,
                              void* d_out, int out_size, void* d_ws, size_t ws_size,
                              hipStream_t stream) {
    const float* x     = (const float*)d_in[0];
    const float* W_ih  = (const float*)d_in[1];
    const float* W_hh  = (const float*)d_in[2];
    const float* b_ih  = (const float*)d_in[3];
    const float* b_hh  = (const float*)d_in[4];
    const float* W_lin = (const float*)d_in[5];
    const float* b_lin = (const float*)d_in[6];
    float* out = (float*)d_out;

    const int B = in_sizes[0] / 512;   // 8192
    dim3 grid(B / 16), block(256);
    lstm_ct4<<<grid, block, 0, stream>>>(x, W_ih, W_hh, b_ih, b_hh, W_lin, b_lin, out);
}

// Round 13
// 218.635 us; speedup vs baseline: 1.4235x; 1.0152x over previous
//
#include <hip/hip_runtime.h>

// LSTM B=8192, T=512, I=1, H=32; out[b] = h_T . W_lin + b_lin.  All I/O f32.
//
// MFMA formulation, 4 waves per 16-batch group (512 blocks x 256 threads),
// custom tiles (zero MFMA duplication), 2 hiddens/lane, fused-rcp acts,
// PAIRED rcp across the lane's two hiddens (scalar math otherwise — the
// R12 packed-f32x2 variant failed the post-timing determinism check; this
// is the R11 green kernel + paired-rcp only).
//
// Wave wv owns hiddens [8wv, 8wv+8). Lane (quad,col) owns j0 = 8wv+2quad+0
// and j1 = j0+1 of batch col. Custom A-tile tau: row m = 4a+r holds W_hh
// gate-row [type r][hidden 8wv+2a+tau] (row-permuting A permutes D rows
// identically), so acc[tau] slots 0..3 = {i,f,g,o} of hidden j0+tau.
// 2 MFMAs/wave-step, no duplication. 2048 waves = 2/SIMD.
//
// Activations (12 trans/lane-step = 10 exp2 + 2 paired rcp):
//   e* = 2^(-z*'), a* = 1+e*;  D = aF*aI*aG per hidden
//   paired: r = rcp(D0*D1); 1/D0 = r*D1, 1/D1 = r*D0
//   c' = (c*aI*aG + (1-eG)*aF) / D
//   eC = 2^(-2*L2E*c'); H = aO*(1+eC) paired-rcp; h = (1-eC)/H
// Pre-acts pre-scaled by L2E (2*L2E for the g gate).

#define L2E 1.4426950408889634f

typedef _Float16 f16x8 __attribute__((ext_vector_type(8)));
typedef float    f32x4 __attribute__((ext_vector_type(4)));

__global__ __launch_bounds__(256, 4) void lstm_ct4r(
    const float* __restrict__ x,      // [B*512]
    const float* __restrict__ W_ih,   // [128]
    const float* __restrict__ W_hh,   // [128*32]
    const float* __restrict__ b_ih,   // [128]
    const float* __restrict__ b_hh,   // [128]
    const float* __restrict__ W_lin,  // [32]
    const float* __restrict__ b_lin,  // [1]
    float* __restrict__ out)          // [B]
{
    __shared__ float xs[512 * 17];                        // x transposed [t][b], stride 17
    __shared__ __align__(16) unsigned int hb[2][16 * 20]; // h half2 buffers, col-stride 20 uints
    __shared__ float ps[64];                              // epilogue partials

    const int tid  = threadIdx.x;
    const int wv   = tid >> 6;         // 0..3: owns hiddens [8wv, 8wv+8)
    const int lane = tid & 63;
    const int col  = lane & 15;        // batch within group
    const int quad = lane >> 4;        // 0..3
    const int base = blockIdx.x * 16;  // global batch base

    // ---- stage x[base..base+15][0..511] into LDS transposed ----
    {
        const float4* xg = (const float4*)(x + (size_t)base * 512);
        #pragma unroll
        for (int it = 0; it < 8; ++it) {
            int idx = it * 256 + tid;          // 0..2047 float4s
            float4 v = xg[idx];
            int b  = idx >> 7;                 // batch 0..15
            int t0 = (idx & 127) * 4;
            xs[(t0 + 0) * 17 + b] = v.x;
            xs[(t0 + 1) * 17 + b] = v.y;
            xs[(t0 + 2) * 17 + b] = v.z;
            xs[(t0 + 3) * 17 + b] = v.w;
        }
    }

    // ---- custom A-tiles: tile tau row m=4a+rt -> W_hh[32*rt + 8wv+2a+tau] ----
    f16x8 wA[2];
    #pragma unroll
    for (int tau = 0; tau < 2; ++tau) {
        const int rt = col & 3;                           // gate type of row col
        const float s = (rt == 2) ? (2.0f * L2E) : L2E;
        const int grow = 32 * rt + 8 * wv + 2 * (col >> 2) + tau;
        #pragma unroll
        for (int j = 0; j < 8; ++j)
            wA[tau][j] = (_Float16)(W_hh[grow * 32 + quad * 8 + j] * s);
    }
    // C-init constants: acc[tau] slot r = gate type r of hidden j0+tau
    const int j0 = 8 * wv + 2 * quad;                     // first owned hidden
    float wih[2][4], bia[2][4];
    #pragma unroll
    for (int tau = 0; tau < 2; ++tau)
        #pragma unroll
        for (int r = 0; r < 4; ++r) {
            const float s = (r == 2) ? (2.0f * L2E) : L2E;
            const int g = 32 * r + j0 + tau;
            wih[tau][r] = W_ih[g] * s;
            bia[tau][r] = (b_ih[g] + b_hh[g]) * s;
        }
    const float wl0 = W_lin[j0], wl1 = W_lin[j0 + 1];

    __syncthreads();

    float c0 = 0.0f, c1 = 0.0f, h0 = 0.0f, h1 = 0.0f;
    f16x8 bfrag = {};                  // h = 0
    f32x4 cq[2];
    {
        float xt = xs[col];            // t = 0
        #pragma unroll
        for (int tau = 0; tau < 2; ++tau)
            #pragma unroll
            for (int r = 0; r < 4; ++r)
                cq[tau][r] = fmaf(xt, wih[tau][r], bia[tau][r]);
    }

    const int wr = col * 20 + 4 * wv + quad;   // h-pair write index (= j0/2 slot)

    #pragma unroll 4
    for (int t = 0; t < 512; ++t) {
        unsigned int* buf = hb[t & 1];

        f32x4 a0 = __builtin_amdgcn_mfma_f32_16x16x32_f16(wA[0], bfrag, cq[0], 0, 0, 0);
        f32x4 a1 = __builtin_amdgcn_mfma_f32_16x16x32_f16(wA[1], bfrag, cq[1], 0, 0, 0);

        float xt1 = xs[((t + 1) & 511) * 17 + col];       // prefetch next x

        // fused activations, hidden j0 (a0) and j0+1 (a1); rcps PAIRED
        float ei0 = __builtin_amdgcn_exp2f(-a0[0]);
        float ef0 = __builtin_amdgcn_exp2f(-a0[1]);
        float eg0 = __builtin_amdgcn_exp2f(-a0[2]);
        float eo0 = __builtin_amdgcn_exp2f(-a0[3]);
        float ei1 = __builtin_amdgcn_exp2f(-a1[0]);
        float ef1 = __builtin_amdgcn_exp2f(-a1[1]);
        float eg1 = __builtin_amdgcn_exp2f(-a1[2]);
        float eo1 = __builtin_amdgcn_exp2f(-a1[3]);
        float aI0 = 1.0f + ei0, aF0 = 1.0f + ef0, aG0 = 1.0f + eg0, aO0 = 1.0f + eo0;
        float aI1 = 1.0f + ei1, aF1 = 1.0f + ef1, aG1 = 1.0f + eg1, aO1 = 1.0f + eo1;
        float tIG0 = aI0 * aG0, tIG1 = aI1 * aG1;
        float num0 = fmaf(c0, tIG0, (1.0f - eg0) * aF0);
        float num1 = fmaf(c1, tIG1, (1.0f - eg1) * aF1);
        float D0 = aF0 * tIG0, D1 = aF1 * tIG1;
        float rD = __builtin_amdgcn_rcpf(D0 * D1);        // paired rcp #1
        c0 = num0 * (rD * D1);
        c1 = num1 * (rD * D0);
        float ec0 = __builtin_amdgcn_exp2f(c0 * (-2.0f * L2E));
        float ec1 = __builtin_amdgcn_exp2f(c1 * (-2.0f * L2E));
        float H0 = aO0 * (1.0f + ec0), H1 = aO1 * (1.0f + ec1);
        float rH = __builtin_amdgcn_rcpf(H0 * H1);        // paired rcp #2
        h0 = (1.0f - ec0) * (rH * H1);
        h1 = (1.0f - ec1) * (rH * H0);

        // adjacent hiddens -> one b32 write of the packed pair
        buf[wr] = __builtin_bit_cast(unsigned int, __builtin_amdgcn_cvt_pkrtz(h0, h1));

        // next step's C-init in the pre-barrier slack
        #pragma unroll
        for (int tau = 0; tau < 2; ++tau)
            #pragma unroll
            for (int r = 0; r < 4; ++r)
                cq[tau][r] = fmaf(xt1, wih[tau][r], bia[tau][r]);

        __syncthreads();
        // B-frag: pairs quad*4..+3 of batch col = k quad*8..quad*8+7
        uint4 bv = *(const uint4*)&buf[col * 20 + quad * 4];
        bfrag = __builtin_bit_cast(f16x8, bv);
    }

    // ---- epilogue: out[b] = sum_j h_j * W_lin[j] + b_lin ----
    float v = fmaf(h0, wl0, h1 * wl1);
    v += __shfl_xor(v, 16);            // combine quads
    v += __shfl_xor(v, 32);
    if (lane < 16) ps[wv * 16 + col] = v;
    __syncthreads();
    if (tid < 16)
        out[base + tid] = b_lin[0] + ps[tid] + ps[16 + tid] + ps[32 + tid] + ps[48 + tid];
}

extern "C" void kernel_launch(void* const* d_in, const int* in_sizes, int n_in,
                              void* d_out, int out_size, void* d_ws, size_t ws_size,
                              hipStream_t stream) {
    const float* x     = (const float*)d_in[0];
    const float* W_ih  = (const float*)d_in[1];
    const float* W_hh  = (const float*)d_in[2];
    const float* b_ih  = (const float*)d_in[3];
    const float* b_hh  = (const float*)d_in[4];
    const float* W_lin = (const float*)d_in[5];
    const float* b_lin = (const float*)d_in[6];
    float* out = (float*)d_out;

    const int B = in_sizes[0] / 512;   // 8192
    dim3 grid(B / 16), block(256);
    lstm_ct4r<<<grid, block, 0, stream>>>(x, W_ih, W_hh, b_ih, b_hh, W_lin, b_lin, out);
}